// Round 1
// baseline (3265.189 us; speedup 1.0000x reference)
//
#include <hip/hip_runtime.h>
#include <math.h>

#define B_SZ 2
#define SEQ  1024
#define DM   1024
#define DI   2048
#define NST  16
#define RNK  64
#define XPD  96            // RNK + 2*NST
#define M_TOT (B_SZ*SEQ)   // 2048

// ---------------------------------------------------------------------------
// Generic fp32 NT SGEMM: D = scale * (A[M,K] * W[N,K]^T)  (+= if accum)
// flipA:  A row m=b*SEQ+l reads source row b*SEQ+(SEQ-1-l)
// flipOut: D row written to b*SEQ+(SEQ-1-l)
// Tile 64x64x16, 256 threads, 4x4 micro-tile per thread.
// ---------------------------------------------------------------------------
#define BM 64
#define BN 64
#define BK 16

__global__ __launch_bounds__(256)
void gemm_nt(const float* __restrict__ A, const float* __restrict__ W,
             float* __restrict__ D, int M, int N, int K,
             int flipA, int flipOut, float scale, int accum)
{
    __shared__ float As[BK][BM + 1];
    __shared__ float Ws[BK][BN + 1];
    int t  = threadIdx.x;
    int m0 = blockIdx.y * BM;
    int n0 = blockIdx.x * BN;
    int lm = t >> 2;           // 0..63 : row within tile
    int lk = (t & 3) << 2;     // 0,4,8,12 : k-quad within tile
    int tm = t >> 4;           // 0..15
    int tn = t & 15;           // 0..15

    float acc[4][4];
#pragma unroll
    for (int i = 0; i < 4; i++)
#pragma unroll
        for (int j = 0; j < 4; j++) acc[i][j] = 0.f;

    int am = m0 + lm;
    int arow;
    {
        int b = am / SEQ, l = am % SEQ;
        arow = flipA ? (b * SEQ + (SEQ - 1 - l)) : am;
    }
    int wn = n0 + lm;
    const float* Aptr = A + arow * K + lk;
    const float* Wptr = (wn < N) ? (W + wn * K + lk) : nullptr;

    for (int k0 = 0; k0 < K; k0 += BK) {
        float4 av = *(const float4*)(Aptr + k0);
        float4 wv = make_float4(0.f, 0.f, 0.f, 0.f);
        if (Wptr) wv = *(const float4*)(Wptr + k0);
        As[lk + 0][lm] = av.x; As[lk + 1][lm] = av.y;
        As[lk + 2][lm] = av.z; As[lk + 3][lm] = av.w;
        Ws[lk + 0][lm] = wv.x; Ws[lk + 1][lm] = wv.y;
        Ws[lk + 2][lm] = wv.z; Ws[lk + 3][lm] = wv.w;
        __syncthreads();
#pragma unroll
        for (int kk = 0; kk < BK; kk++) {
            float a[4], w[4];
#pragma unroll
            for (int i = 0; i < 4; i++) a[i] = As[kk][tm * 4 + i];
#pragma unroll
            for (int j = 0; j < 4; j++) w[j] = Ws[kk][tn * 4 + j];
#pragma unroll
            for (int i = 0; i < 4; i++)
#pragma unroll
                for (int j = 0; j < 4; j++) acc[i][j] += a[i] * w[j];
        }
        __syncthreads();
    }

#pragma unroll
    for (int i = 0; i < 4; i++) {
        int m = m0 + tm * 4 + i;
        int b = m / SEQ, l = m % SEQ;
        int mo = flipOut ? (b * SEQ + (SEQ - 1 - l)) : m;
#pragma unroll
        for (int j = 0; j < 4; j++) {
            int n = n0 + tn * 4 + j;
            if (n < N) {
                float v = scale * acc[i][j];
                int idx = mo * N + n;
                if (accum) D[idx] += v; else D[idx] = v;
            }
        }
    }
}

// ---------------------------------------------------------------------------
// Depthwise causal conv(4) + bias + SiLU.  xi = xz[:, 0:DI] (row stride 2*DI)
// ---------------------------------------------------------------------------
__global__ __launch_bounds__(256)
void conv_silu(const float* __restrict__ xz, const float* __restrict__ convW,
               const float* __restrict__ convB, float* __restrict__ u)
{
    int idx = blockIdx.x * 256 + threadIdx.x;  // over M_TOT*DI, di fastest
    int di = idx & (DI - 1);
    int m  = idx >> 11;
    int b  = m >> 10, l = m & (SEQ - 1);
    float acc = convB[di];
#pragma unroll
    for (int j = 0; j < 4; j++) {
        int ll = l - 3 + j;
        if (ll >= 0) acc += convW[di * 4 + j] * xz[(b * SEQ + ll) * (2 * DI) + di];
    }
    u[m * DI + di] = acc / (1.f + __expf(-acc));   // silu
}

// ---------------------------------------------------------------------------
// delta = softplus(dt[M,64] * dtW[DI,64]^T + dtB)   (dt = xdbl[:, 0:64])
// One block per (di-tile of 256, m).  dt row cached in LDS.
// ---------------------------------------------------------------------------
__global__ __launch_bounds__(256)
void delta_kernel(const float* __restrict__ xdbl, const float* __restrict__ dtW,
                  const float* __restrict__ dtB, float* __restrict__ delta)
{
    __shared__ float sdt[RNK];
    int m = blockIdx.y;
    int t = threadIdx.x;
    if (t < RNK) sdt[t] = xdbl[m * XPD + t];
    __syncthreads();
    int di = blockIdx.x * 256 + t;
    float acc = dtB[di];
#pragma unroll
    for (int r = 0; r < RNK; r++) acc += sdt[r] * dtW[di * RNK + r];
    float sp = (acc > 20.f) ? acc : log1pf(__expf(acc));
    delta[m * DI + di] = sp;
}

// ---------------------------------------------------------------------------
// Selective scan + fused epilogue: y = (scan + u*Dp) * silu(z)
// 1024 waves; wave = (b, 4 consecutive d); lane = g*16 + n (g=chain, n=state).
// h recurrence in registers; y reduction over n via shfl_xor butterfly.
// ---------------------------------------------------------------------------
__global__ __launch_bounds__(256)
void scan_kernel(const float* __restrict__ xz, const float* __restrict__ u,
                 const float* __restrict__ xdbl, const float* __restrict__ delta,
                 const float* __restrict__ Alog, const float* __restrict__ Dp,
                 float* __restrict__ y)
{
    int tid  = threadIdx.x;
    int w    = blockIdx.x * 4 + (tid >> 6);   // 0..1023
    int lane = tid & 63;
    int g = lane >> 4, n = lane & 15;
    int b = w >> 9;
    int d = ((w & 511) << 2) + g;

    float a_coef = -__expf(Alog[d * NST + n]);   // A = -exp(Alog)
    float dp = Dp[d];
    float h = 0.f;

    const float* dlt = delta + b * SEQ * DI + d;
    const float* up  = u     + b * SEQ * DI + d;
    const float* xd  = xdbl  + b * SEQ * XPD;
    const float* zz  = xz    + b * SEQ * (2 * DI) + DI + d;
    float*       yp  = y     + b * SEQ * DI + d;

    for (int l = 0; l < SEQ; l++) {
        float dly = dlt[l * DI];
        float uv  = up[l * DI];
        float Bv  = xd[l * XPD + RNK + n];
        float Cv  = xd[l * XPD + RNK + NST + n];
        float dA  = __expf(dly * a_coef);
        h = h * dA + (dly * uv) * Bv;
        float p = h * Cv;
        p += __shfl_xor(p, 1);
        p += __shfl_xor(p, 2);
        p += __shfl_xor(p, 4);
        p += __shfl_xor(p, 8);
        if (n == 0) {
            float yv = p + uv * dp;
            float z  = zz[l * (2 * DI)];
            yv *= z / (1.f + __expf(-z));
            yp[l * DI] = yv;
        }
    }
}

// ---------------------------------------------------------------------------
extern "C" void kernel_launch(void* const* d_in, const int* in_sizes, int n_in,
                              void* d_out, int out_size, void* d_ws, size_t ws_size,
                              hipStream_t stream)
{
    const float* x = (const float*)d_in[0];
    float* ws    = (float*)d_ws;
    float* xz    = ws;                          // 2048*4096 = 8.39M floats
    float* u     = xz    + M_TOT * 2 * DI;      // 2048*2048
    float* xdbl  = u     + M_TOT * DI;          // 2048*96
    float* delta = xdbl  + M_TOT * XPD;         // 2048*2048
    float* y     = delta + M_TOT * DI;          // 2048*2048
    float* out   = (float*)d_out;

    dim3 blk(256);
    for (int dir = 0; dir < 2; dir++) {
        int pb = 1 + dir * 9;
        const float* inW   = (const float*)d_in[pb + 0];
        const float* convW = (const float*)d_in[pb + 1];
        const float* convB = (const float*)d_in[pb + 2];
        const float* xpW   = (const float*)d_in[pb + 3];
        const float* dtW   = (const float*)d_in[pb + 4];
        const float* dtB   = (const float*)d_in[pb + 5];
        const float* Alog  = (const float*)d_in[pb + 6];
        const float* Dp    = (const float*)d_in[pb + 7];
        const float* outW  = (const float*)d_in[pb + 8];

        // xz = X(dir) * inW^T   [2048 x 4096], K=1024
        gemm_nt<<<dim3((2 * DI) / BN, M_TOT / BM), blk, 0, stream>>>(
            x, inW, xz, M_TOT, 2 * DI, DM, dir, 0, 1.f, 0);

        // u = silu(causal_conv(xi) + convB)
        conv_silu<<<(M_TOT * DI) / 256, blk, 0, stream>>>(xz, convW, convB, u);

        // xdbl = u * xpW^T   [2048 x 96], K=2048
        gemm_nt<<<dim3((XPD + BN - 1) / BN, M_TOT / BM), blk, 0, stream>>>(
            u, xpW, xdbl, M_TOT, XPD, DI, 0, 0, 1.f, 0);

        // delta = softplus(dt * dtW^T + dtB)
        delta_kernel<<<dim3(DI / 256, M_TOT), blk, 0, stream>>>(xdbl, dtW, dtB, delta);

        // selective scan + (y + u*Dp)*silu(z)
        scan_kernel<<<256, blk, 0, stream>>>(xz, u, xdbl, delta, Alog, Dp, y);

        // out (+)= 0.5 * y * outW^T, rows un-flipped for dir=1
        gemm_nt<<<dim3(DM / BN, M_TOT / BM), blk, 0, stream>>>(
            y, outW, out, M_TOT, DM, DI, 0, dir, 0.5f, dir);
    }
}

// Round 2
// 1240.154 us; speedup vs baseline: 2.6329x; 2.6329x over previous
//
#include <hip/hip_runtime.h>
#include <math.h>

#define B_SZ 2
#define SEQ  1024
#define DM   1024
#define DI   2048
#define NST  16
#define RNK  64
#define XPD  96            // RNK + 2*NST
#define M_TOT (B_SZ*SEQ)   // 2048

typedef unsigned short ushort_t;
typedef __attribute__((ext_vector_type(8))) short short8;   // 8 bf16 = 4 VGPRs
typedef __attribute__((ext_vector_type(4))) float f32x4;

__device__ __forceinline__ ushort_t f2bf(float f) {
    unsigned u = __float_as_uint(f);
    u += 0x7fff + ((u >> 16) & 1);           // round-to-nearest-even
    return (ushort_t)(u >> 16);
}

// ---------------------------------------------------------------------------
// fp32 -> bf16 bulk convert (n must be multiple of 1024; processes float4)
// ---------------------------------------------------------------------------
__global__ __launch_bounds__(256)
void f32_to_bf16(const float* __restrict__ in, ushort_t* __restrict__ out)
{
    int i = blockIdx.x * 256 + threadIdx.x;
    float4 v = ((const float4*)in)[i];
    ushort4 o;
    o.x = f2bf(v.x); o.y = f2bf(v.y); o.z = f2bf(v.z); o.w = f2bf(v.w);
    ((ushort4*)out)[i] = o;
}

// ---------------------------------------------------------------------------
// bf16 MFMA NT GEMM: D[M,N] = scale * (A[M,K] * W[N,K]^T) (+= if accum)
// A,W bf16 row-major (row stride K); D fp32. flipA remaps A source rows
// b*SEQ+l -> b*SEQ+(SEQ-1-l); flipOut remaps store rows the same way.
// 256 threads = 4 waves in 2x2; tile BMxBN, BK=64; mfma_f32_16x16x32_bf16.
// Frag layouts [measured m89/m91/m120]: A/B lane holds 8 contig K elems at
// row (lane&15), k=(lane>>4)*8; C/D col=lane&15, row=(lane>>4)*4+reg.
// ---------------------------------------------------------------------------
#define BK   64
#define LDSP 72   // padded LDS row stride (bf16 elems); 144 B, 16B-aligned

template<int BM, int BN>
__global__ __launch_bounds__(256)
void gemm_mfma(const ushort_t* __restrict__ A, const ushort_t* __restrict__ W,
               float* __restrict__ D, int M, int N, int K,
               int flipA, int flipOut, float scale, int accum)
{
    __shared__ __align__(16) ushort_t As[BM * LDSP];
    __shared__ __align__(16) ushort_t Ws[BN * LDSP];
    const int t    = threadIdx.x;
    const int lane = t & 63;
    const int wave = t >> 6;
    const int wr   = (wave >> 1) * (BM / 2);   // wave row offset in tile
    const int wc   = (wave & 1) * (BN / 2);    // wave col offset in tile
    constexpr int MT = BM / 32;                // 16-tiles per wave (m)
    constexpr int NTW = BN / 32;               // 16-tiles per wave (n)

    f32x4 acc[MT][NTW] = {};

    const int m0 = blockIdx.y * BM;
    const int n0 = blockIdx.x * BN;
    const int srow = t >> 3;            // staging row within 32-row group
    const int scol = (t & 7) << 3;      // staging col (bf16 elems)

    for (int k0 = 0; k0 < K; k0 += BK) {
#pragma unroll
        for (int it = 0; it < BM / 32; it++) {
            int r = it * 32 + srow;
            int m = m0 + r;
            int arow = m;
            if (flipA) { int b = m >> 10, l = m & 1023; arow = (b << 10) + (1023 - l); }
            short8 v = *(const short8*)(A + (size_t)arow * K + k0 + scol);
            *(short8*)(&As[r * LDSP + scol]) = v;
        }
#pragma unroll
        for (int it = 0; it < BN / 32; it++) {
            int r = it * 32 + srow;
            int wn = n0 + r;
            short8 v = {};
            if (wn < N) v = *(const short8*)(W + (size_t)wn * K + k0 + scol);
            *(short8*)(&Ws[r * LDSP + scol]) = v;
        }
        __syncthreads();
#pragma unroll
        for (int kk = 0; kk < 2; kk++) {
            const int kc = kk * 32 + ((lane >> 4) << 3);
            short8 af[MT], bfr[NTW];
#pragma unroll
            for (int i = 0; i < MT; i++)
                af[i] = *(const short8*)(&As[(wr + i * 16 + (lane & 15)) * LDSP + kc]);
#pragma unroll
            for (int j = 0; j < NTW; j++)
                bfr[j] = *(const short8*)(&Ws[(wc + j * 16 + (lane & 15)) * LDSP + kc]);
#pragma unroll
            for (int i = 0; i < MT; i++)
#pragma unroll
                for (int j = 0; j < NTW; j++)
                    acc[i][j] = __builtin_amdgcn_mfma_f32_16x16x32_bf16(
                        af[i], bfr[j], acc[i][j], 0, 0, 0);
        }
        __syncthreads();
    }

#pragma unroll
    for (int i = 0; i < MT; i++) {
#pragma unroll
        for (int r = 0; r < 4; r++) {
            int m = m0 + wr + i * 16 + ((lane >> 4) << 2) + r;
            int b = m >> 10, l = m & 1023;
            int mo = flipOut ? ((b << 10) + (1023 - l)) : m;
#pragma unroll
            for (int j = 0; j < NTW; j++) {
                int n = n0 + wc + j * 16 + (lane & 15);
                if (n < N) {
                    float v = scale * acc[i][j][r];
                    size_t idx = (size_t)mo * N + n;
                    if (accum) D[idx] += v; else D[idx] = v;
                }
            }
        }
    }
}

// ---------------------------------------------------------------------------
// Depthwise causal conv(4) + bias + SiLU. xi = xz[:, 0:DI] (row stride 2*DI).
// Emits u (fp32, for scan) and ubf (bf16, for GEMM2).
// ---------------------------------------------------------------------------
__global__ __launch_bounds__(256)
void conv_silu(const float* __restrict__ xz, const float* __restrict__ convW,
               const float* __restrict__ convB, float* __restrict__ u,
               ushort_t* __restrict__ ubf)
{
    int idx = blockIdx.x * 256 + threadIdx.x;  // over M_TOT*DI, di fastest
    int di = idx & (DI - 1);
    int m  = idx >> 11;
    int b  = m >> 10, l = m & (SEQ - 1);
    float acc = convB[di];
#pragma unroll
    for (int j = 0; j < 4; j++) {
        int ll = l - 3 + j;
        if (ll >= 0) acc += convW[di * 4 + j] * xz[(size_t)(b * SEQ + ll) * (2 * DI) + di];
    }
    float s = acc / (1.f + __expf(-acc));
    u[(size_t)m * DI + di] = s;
    ubf[(size_t)m * DI + di] = f2bf(s);
}

// ---------------------------------------------------------------------------
// delta = softplus(dt[M,64] * dtW[DI,64]^T + dtB)   (dt = xdbl[:, 0:64])
// ---------------------------------------------------------------------------
__global__ __launch_bounds__(256)
void delta_kernel(const float* __restrict__ xdbl, const float* __restrict__ dtW,
                  const float* __restrict__ dtB, float* __restrict__ delta)
{
    __shared__ float sdt[RNK];
    int m = blockIdx.y;
    int t = threadIdx.x;
    if (t < RNK) sdt[t] = xdbl[(size_t)m * XPD + t];
    __syncthreads();
    int di = blockIdx.x * 256 + t;
    float acc = dtB[di];
#pragma unroll
    for (int r = 0; r < RNK; r++) acc += sdt[r] * dtW[di * RNK + r];
    float sp = (acc > 20.f) ? acc : log1pf(__expf(acc));
    delta[(size_t)m * DI + di] = sp;
}

// ---------------------------------------------------------------------------
// Selective scan + fused epilogue: y = (scan + u*Dp) * silu(z), emitted bf16.
// 1024 waves; wave = (b, 4 consecutive d); lane = g*16 + n.
// Software-pipelined: double-buffered registers, prefetch next 8 steps'
// operands while computing current 8 (h-chain is the only true dependence).
// ---------------------------------------------------------------------------
#define U 8

#define SCAN_LOADS(P, L0)                                  \
    _Pragma("unroll")                                      \
    for (int j = 0; j < U; j++) {                          \
        int l = (L0) + j;                                  \
        P##_d[j] = dlt[l * DI];                            \
        P##_u[j] = up[l * DI];                             \
        P##_B[j] = xd[l * XPD];                            \
        P##_C[j] = xd[l * XPD + NST];                      \
        P##_z[j] = zz[l * (2 * DI)];                       \
    }

#define SCAN_STEPS(P, L0)                                  \
    _Pragma("unroll")                                      \
    for (int j = 0; j < U; j++) {                          \
        float dl = P##_d[j];                               \
        float dA = __expf(dl * a_coef);                    \
        h = h * dA + (dl * P##_u[j]) * P##_B[j];           \
        float p = h * P##_C[j];                            \
        p += __shfl_xor(p, 1);                             \
        p += __shfl_xor(p, 2);                             \
        p += __shfl_xor(p, 4);                             \
        p += __shfl_xor(p, 8);                             \
        if (n == 0) {                                      \
            float yv = p + P##_u[j] * dp;                  \
            float z = P##_z[j];                            \
            yv *= z / (1.f + __expf(-z));                  \
            yp[((L0) + j) * DI] = f2bf(yv);                \
        }                                                  \
    }

__global__ __launch_bounds__(256)
void scan_kernel(const float* __restrict__ xz, const float* __restrict__ u,
                 const float* __restrict__ xdbl, const float* __restrict__ delta,
                 const float* __restrict__ Alog, const float* __restrict__ Dp,
                 ushort_t* __restrict__ ybf)
{
    int tid  = threadIdx.x;
    int w    = blockIdx.x * 4 + (tid >> 6);   // 0..1023
    int lane = tid & 63;
    int g = lane >> 4, n = lane & 15;
    int b = w >> 9;
    int d = ((w & 511) << 2) + g;

    float a_coef = -__expf(Alog[d * NST + n]);   // A = -exp(Alog)
    float dp = Dp[d];
    float h = 0.f;

    const float* dlt = delta + (size_t)b * SEQ * DI + d;
    const float* up  = u     + (size_t)b * SEQ * DI + d;
    const float* xd  = xdbl  + (size_t)b * SEQ * XPD + RNK + n;
    const float* zz  = xz    + (size_t)b * SEQ * (2 * DI) + DI + d;
    ushort_t*    yp  = ybf   + (size_t)b * SEQ * DI + d;

    float pa_d[U], pa_u[U], pa_B[U], pa_C[U], pa_z[U];
    float pb_d[U], pb_u[U], pb_B[U], pb_C[U], pb_z[U];

    SCAN_LOADS(pa, 0);
    for (int l0 = 0; l0 < SEQ; l0 += 2 * U) {
        SCAN_LOADS(pb, l0 + U);                       // l0+U <= 1016 < SEQ always
        SCAN_STEPS(pa, l0);
        if (l0 + 2 * U < SEQ) { SCAN_LOADS(pa, l0 + 2 * U); }
        SCAN_STEPS(pb, l0 + U);
    }
}

// ---------------------------------------------------------------------------
extern "C" void kernel_launch(void* const* d_in, const int* in_sizes, int n_in,
                              void* d_out, int out_size, void* d_ws, size_t ws_size,
                              hipStream_t stream)
{
    const float* x = (const float*)d_in[0];
    float* wsf = (float*)d_ws;

    // fp32 region (elements)
    float* xz    = wsf;                         // 2048*4096  = 8388608
    float* u     = xz   + (size_t)M_TOT * 2 * DI; // 4194304
    float* xdbl  = u    + (size_t)M_TOT * DI;     // 196608
    float* delta = xdbl + (size_t)M_TOT * XPD;    // 4194304
    // bf16 region
    ushort_t* bfr    = (ushort_t*)(delta + (size_t)M_TOT * DI);
    ushort_t* xbf    = bfr;                              // 2097152
    ushort_t* ubf    = xbf   + (size_t)M_TOT * DM;       // 4194304
    ushort_t* ybf    = ubf   + (size_t)M_TOT * DI;       // 4194304
    ushort_t* inWbf  = ybf   + (size_t)M_TOT * DI;       // 4194304
    ushort_t* xpWbf  = inWbf + (size_t)2 * DI * DM;      // 196608
    ushort_t* outWbf = xpWbf + (size_t)XPD * DI;         // 2097152

    float* out = (float*)d_out;
    dim3 blk(256);

    // x -> bf16 once
    f32_to_bf16<<<(M_TOT * DM) / 1024, blk, 0, stream>>>(x, xbf);

    for (int dir = 0; dir < 2; dir++) {
        int pb = 1 + dir * 9;
        const float* inW   = (const float*)d_in[pb + 0];
        const float* convW = (const float*)d_in[pb + 1];
        const float* convB = (const float*)d_in[pb + 2];
        const float* xpW   = (const float*)d_in[pb + 3];
        const float* dtW   = (const float*)d_in[pb + 4];
        const float* dtB   = (const float*)d_in[pb + 5];
        const float* Alog  = (const float*)d_in[pb + 6];
        const float* Dp    = (const float*)d_in[pb + 7];
        const float* outW  = (const float*)d_in[pb + 8];

        // weight conversions
        f32_to_bf16<<<(2 * DI * DM) / 1024, blk, 0, stream>>>(inW, inWbf);
        f32_to_bf16<<<(XPD * DI) / 1024, blk, 0, stream>>>(xpW, xpWbf);
        f32_to_bf16<<<(DM * DI) / 1024, blk, 0, stream>>>(outW, outWbf);

        // xz = X(dir) * inW^T   [2048 x 4096], K=1024
        gemm_mfma<128, 128><<<dim3((2 * DI) / 128, M_TOT / 128), blk, 0, stream>>>(
            xbf, inWbf, xz, M_TOT, 2 * DI, DM, dir, 0, 1.f, 0);

        // u = silu(causal_conv(xi) + convB)  (fp32 + bf16)
        conv_silu<<<(M_TOT * DI) / 256, blk, 0, stream>>>(xz, convW, convB, u, ubf);

        // xdbl = u * xpW^T   [2048 x 96], K=2048
        gemm_mfma<64, 64><<<dim3((XPD + 63) / 64, M_TOT / 64), blk, 0, stream>>>(
            ubf, xpWbf, xdbl, M_TOT, XPD, DI, 0, 0, 1.f, 0);

        // delta = softplus(dt * dtW^T + dtB)
        delta_kernel<<<dim3(DI / 256, M_TOT), blk, 0, stream>>>(xdbl, dtW, dtB, delta);

        // selective scan + (y + u*Dp)*silu(z) -> bf16
        scan_kernel<<<256, blk, 0, stream>>>(xz, u, xdbl, delta, Alog, Dp, ybf);

        // out (+)= 0.5 * y * outW^T, rows un-flipped for dir=1
        gemm_mfma<64, 64><<<dim3(DM / 64, M_TOT / 64), blk, 0, stream>>>(
            ybf, outWbf, out, M_TOT, DM, DI, 0, dir, 0.5f, dir);
    }
}

// Round 3
// 937.636 us; speedup vs baseline: 3.4824x; 1.3226x over previous
//
#include <hip/hip_runtime.h>
#include <math.h>

#define B_SZ 2
#define SEQ  1024
#define DM   1024
#define DI   2048
#define NST  16
#define RNK  64
#define XPD  96            // RNK + 2*NST
#define M_TOT (B_SZ*SEQ)   // 2048
#define NC   16            // scan chunks
#define LC   (SEQ/NC)      // 64 steps per chunk
#define NCH  65536         // total chains = B_SZ*DI*NST

typedef unsigned short ushort_t;
typedef __attribute__((ext_vector_type(8))) short short8;   // 8 bf16 = 4 VGPRs
typedef __attribute__((ext_vector_type(4))) float f32x4;

__device__ __forceinline__ ushort_t f2bf(float f) {
    unsigned u = __float_as_uint(f);
    u += 0x7fff + ((u >> 16) & 1);           // round-to-nearest-even
    return (ushort_t)(u >> 16);
}

// ---------------------------------------------------------------------------
// fp32 -> bf16 bulk convert (n must be multiple of 1024; processes float4)
// ---------------------------------------------------------------------------
__global__ __launch_bounds__(256)
void f32_to_bf16(const float* __restrict__ in, ushort_t* __restrict__ out)
{
    int i = blockIdx.x * 256 + threadIdx.x;
    float4 v = ((const float4*)in)[i];
    ushort4 o;
    o.x = f2bf(v.x); o.y = f2bf(v.y); o.z = f2bf(v.z); o.w = f2bf(v.w);
    ((ushort4*)out)[i] = o;
}

// ---------------------------------------------------------------------------
// bf16 MFMA NT GEMM: D[M,N] = scale * (A[M,K] * W[N,K]^T) (+= if accum)
// ---------------------------------------------------------------------------
#define BK   64
#define LDSP 72   // padded LDS row stride (bf16 elems)

template<int BM, int BN>
__global__ __launch_bounds__(256)
void gemm_mfma(const ushort_t* __restrict__ A, const ushort_t* __restrict__ W,
               float* __restrict__ D, int M, int N, int K,
               int flipA, int flipOut, float scale, int accum)
{
    __shared__ __align__(16) ushort_t As[BM * LDSP];
    __shared__ __align__(16) ushort_t Ws[BN * LDSP];
    const int t    = threadIdx.x;
    const int lane = t & 63;
    const int wave = t >> 6;
    const int wr   = (wave >> 1) * (BM / 2);
    const int wc   = (wave & 1) * (BN / 2);
    constexpr int MT  = BM / 32;
    constexpr int NTW = BN / 32;

    f32x4 acc[MT][NTW] = {};

    const int m0 = blockIdx.y * BM;
    const int n0 = blockIdx.x * BN;
    const int srow = t >> 3;
    const int scol = (t & 7) << 3;

    for (int k0 = 0; k0 < K; k0 += BK) {
#pragma unroll
        for (int it = 0; it < BM / 32; it++) {
            int r = it * 32 + srow;
            int m = m0 + r;
            int arow = m;
            if (flipA) { int b = m >> 10, l = m & 1023; arow = (b << 10) + (1023 - l); }
            short8 v = *(const short8*)(A + (size_t)arow * K + k0 + scol);
            *(short8*)(&As[r * LDSP + scol]) = v;
        }
#pragma unroll
        for (int it = 0; it < BN / 32; it++) {
            int r = it * 32 + srow;
            int wn = n0 + r;
            short8 v = {};
            if (wn < N) v = *(const short8*)(W + (size_t)wn * K + k0 + scol);
            *(short8*)(&Ws[r * LDSP + scol]) = v;
        }
        __syncthreads();
#pragma unroll
        for (int kk = 0; kk < 2; kk++) {
            const int kc = kk * 32 + ((lane >> 4) << 3);
            short8 af[MT], bfr[NTW];
#pragma unroll
            for (int i = 0; i < MT; i++)
                af[i] = *(const short8*)(&As[(wr + i * 16 + (lane & 15)) * LDSP + kc]);
#pragma unroll
            for (int j = 0; j < NTW; j++)
                bfr[j] = *(const short8*)(&Ws[(wc + j * 16 + (lane & 15)) * LDSP + kc]);
#pragma unroll
            for (int i = 0; i < MT; i++)
#pragma unroll
                for (int j = 0; j < NTW; j++)
                    acc[i][j] = __builtin_amdgcn_mfma_f32_16x16x32_bf16(
                        af[i], bfr[j], acc[i][j], 0, 0, 0);
        }
        __syncthreads();
    }

#pragma unroll
    for (int i = 0; i < MT; i++) {
#pragma unroll
        for (int r = 0; r < 4; r++) {
            int m = m0 + wr + i * 16 + ((lane >> 4) << 2) + r;
            int b = m >> 10, l = m & 1023;
            int mo = flipOut ? ((b << 10) + (1023 - l)) : m;
#pragma unroll
            for (int j = 0; j < NTW; j++) {
                int n = n0 + wc + j * 16 + (lane & 15);
                if (n < N) {
                    float v = scale * acc[i][j][r];
                    size_t idx = (size_t)mo * N + n;
                    if (accum) D[idx] += v; else D[idx] = v;
                }
            }
        }
    }
}

// ---------------------------------------------------------------------------
// Depthwise causal conv(4) + bias + SiLU -> u (fp32) and ubf (bf16)
// ---------------------------------------------------------------------------
__global__ __launch_bounds__(256)
void conv_silu(const float* __restrict__ xz, const float* __restrict__ convW,
               const float* __restrict__ convB, float* __restrict__ u,
               ushort_t* __restrict__ ubf)
{
    int idx = blockIdx.x * 256 + threadIdx.x;
    int di = idx & (DI - 1);
    int m  = idx >> 11;
    int b  = m >> 10, l = m & (SEQ - 1);
    float acc = convB[di];
#pragma unroll
    for (int j = 0; j < 4; j++) {
        int ll = l - 3 + j;
        if (ll >= 0) acc += convW[di * 4 + j] * xz[(size_t)(b * SEQ + ll) * (2 * DI) + di];
    }
    float s = acc / (1.f + __expf(-acc));
    u[(size_t)m * DI + di] = s;
    ubf[(size_t)m * DI + di] = f2bf(s);
}

// ---------------------------------------------------------------------------
// delta = softplus(dt[M,64] * dtW[DI,64]^T + dtB)
// ---------------------------------------------------------------------------
__global__ __launch_bounds__(256)
void delta_kernel(const float* __restrict__ xdbl, const float* __restrict__ dtW,
                  const float* __restrict__ dtB, float* __restrict__ delta)
{
    __shared__ float sdt[RNK];
    int m = blockIdx.y;
    int t = threadIdx.x;
    if (t < RNK) sdt[t] = xdbl[(size_t)m * XPD + t];
    __syncthreads();
    int di = blockIdx.x * 256 + t;
    float acc = dtB[di];
#pragma unroll
    for (int r = 0; r < RNK; r++) acc += sdt[r] * dtW[di * RNK + r];
    float sp = (acc > 20.f) ? acc : log1pf(__expf(acc));
    delta[(size_t)m * DI + di] = sp;
}

// ---------------------------------------------------------------------------
// Chunked selective scan (exact: linear recurrence split into NC chunks).
// Wave layout (all passes): wave w in 0..1023 = (b, 4 consecutive d);
// lane = g*16+n. Chain id = w*64+lane. Chunk c handled by wave_global =
// c*1024 + w.
// ---------------------------------------------------------------------------
#define U 8

// ---- pass 1: per-chunk (P = prod dA, S = state from 0); no y ----
#define P1_LOADS(P, L0)                                    \
    _Pragma("unroll")                                      \
    for (int j = 0; j < U; j++) {                          \
        int l = (L0) + j;                                  \
        P##_d[j] = dlt[l * DI];                            \
        P##_u[j] = up[l * DI];                             \
        P##_B[j] = xd[l * XPD];                            \
    }

#define P1_STEPS(P)                                        \
    _Pragma("unroll")                                      \
    for (int j = 0; j < U; j++) {                          \
        float dl = P##_d[j];                               \
        float dA = __expf(dl * a_coef);                    \
        h = h * dA + (dl * P##_u[j]) * P##_B[j];           \
        prodP *= dA;                                       \
    }

__global__ __launch_bounds__(256)
void scan_pass1(const float* __restrict__ u, const float* __restrict__ xdbl,
                const float* __restrict__ delta, const float* __restrict__ Alog,
                float* __restrict__ Sb, float* __restrict__ Pb)
{
    int tid = threadIdx.x;
    int wg  = blockIdx.x * 4 + (tid >> 6);
    int w   = wg & 1023;
    int c   = wg >> 10;
    int lane = tid & 63;
    int g = lane >> 4, n = lane & 15;
    int b = w >> 9;
    int d = ((w & 511) << 2) + g;
    int base = c * LC;

    float a_coef = -__expf(Alog[d * NST + n]);
    float h = 0.f, prodP = 1.f;

    const float* dlt = delta + (size_t)b * SEQ * DI + d + (size_t)base * DI;
    const float* up  = u     + (size_t)b * SEQ * DI + d + (size_t)base * DI;
    const float* xd  = xdbl  + (size_t)b * SEQ * XPD + RNK + n + (size_t)base * XPD;

    float pa_d[U], pa_u[U], pa_B[U];
    float pb_d[U], pb_u[U], pb_B[U];

    P1_LOADS(pa, 0);
    for (int l0 = 0; l0 < LC; l0 += 2 * U) {
        P1_LOADS(pb, l0 + U);
        P1_STEPS(pa);
        if (l0 + 2 * U < LC) { P1_LOADS(pa, l0 + 2 * U); }
        P1_STEPS(pb);
    }
    int i = c * NCH + w * 64 + lane;
    Sb[i] = h;
    Pb[i] = prodP;
}

// ---- combine: 16-step serial prefix over chunks, in place (Sb <- h_init) ----
__global__ __launch_bounds__(256)
void scan_combine(float* __restrict__ Sb, const float* __restrict__ Pb)
{
    int i = blockIdx.x * 256 + threadIdx.x;   // 0..NCH-1
    float h = 0.f;
#pragma unroll
    for (int c = 0; c < NC; c++) {
        float s = Sb[c * NCH + i];
        float p = Pb[c * NCH + i];
        Sb[c * NCH + i] = h;
        h = s + p * h;
    }
}

// ---- pass 2: re-run chunk from exact h_init, emit y = (scan+u*Dp)*silu(z) ----
#define SCAN_LOADS(P, L0)                                  \
    _Pragma("unroll")                                      \
    for (int j = 0; j < U; j++) {                          \
        int l = (L0) + j;                                  \
        P##_d[j] = dlt[l * DI];                            \
        P##_u[j] = up[l * DI];                             \
        P##_B[j] = xd[l * XPD];                            \
        P##_C[j] = xd[l * XPD + NST];                      \
        P##_z[j] = zz[l * (2 * DI)];                       \
    }

#define SCAN_STEPS(P, L0)                                  \
    _Pragma("unroll")                                      \
    for (int j = 0; j < U; j++) {                          \
        float dl = P##_d[j];                               \
        float dA = __expf(dl * a_coef);                    \
        h = h * dA + (dl * P##_u[j]) * P##_B[j];           \
        float p = h * P##_C[j];                            \
        p += __shfl_xor(p, 1);                             \
        p += __shfl_xor(p, 2);                             \
        p += __shfl_xor(p, 4);                             \
        p += __shfl_xor(p, 8);                             \
        if (n == 0) {                                      \
            float yv = p + P##_u[j] * dp;                  \
            float z = P##_z[j];                            \
            yv *= z / (1.f + __expf(-z));                  \
            yp[((L0) + j) * DI] = f2bf(yv);                \
        }                                                  \
    }

__global__ __launch_bounds__(256)
void scan_pass2(const float* __restrict__ xz, const float* __restrict__ u,
                const float* __restrict__ xdbl, const float* __restrict__ delta,
                const float* __restrict__ Alog, const float* __restrict__ Dp,
                const float* __restrict__ Hinit, ushort_t* __restrict__ ybf)
{
    int tid  = threadIdx.x;
    int wg   = blockIdx.x * 4 + (tid >> 6);
    int w    = wg & 1023;
    int c    = wg >> 10;
    int lane = tid & 63;
    int g = lane >> 4, n = lane & 15;
    int b = w >> 9;
    int d = ((w & 511) << 2) + g;
    int base = c * LC;

    float a_coef = -__expf(Alog[d * NST + n]);
    float dp = Dp[d];
    float h  = Hinit[c * NCH + w * 64 + lane];

    const float* dlt = delta + (size_t)b * SEQ * DI + d + (size_t)base * DI;
    const float* up  = u     + (size_t)b * SEQ * DI + d + (size_t)base * DI;
    const float* xd  = xdbl  + (size_t)b * SEQ * XPD + RNK + n + (size_t)base * XPD;
    const float* zz  = xz    + (size_t)b * SEQ * (2 * DI) + DI + d + (size_t)base * 2 * DI;
    ushort_t*    yp  = ybf   + (size_t)b * SEQ * DI + d + (size_t)base * DI;

    float pa_d[U], pa_u[U], pa_B[U], pa_C[U], pa_z[U];
    float pb_d[U], pb_u[U], pb_B[U], pb_C[U], pb_z[U];

    SCAN_LOADS(pa, 0);
    for (int l0 = 0; l0 < LC; l0 += 2 * U) {
        SCAN_LOADS(pb, l0 + U);
        SCAN_STEPS(pa, l0);
        if (l0 + 2 * U < LC) { SCAN_LOADS(pa, l0 + 2 * U); }
        SCAN_STEPS(pb, l0 + U);
    }
}

// ---------------------------------------------------------------------------
extern "C" void kernel_launch(void* const* d_in, const int* in_sizes, int n_in,
                              void* d_out, int out_size, void* d_ws, size_t ws_size,
                              hipStream_t stream)
{
    const float* x = (const float*)d_in[0];
    float* wsf = (float*)d_ws;

    // fp32 region (elements)
    float* xz    = wsf;                           // 8388608
    float* u     = xz   + (size_t)M_TOT * 2 * DI; // 4194304
    float* xdbl  = u    + (size_t)M_TOT * DI;     // 196608
    float* delta = xdbl + (size_t)M_TOT * XPD;    // 4194304
    // bf16 region
    ushort_t* bfr    = (ushort_t*)(delta + (size_t)M_TOT * DI);
    ushort_t* xbf    = bfr;                              // 2097152
    ushort_t* ubf    = xbf   + (size_t)M_TOT * DM;       // 4194304
    ushort_t* ybf    = ubf   + (size_t)M_TOT * DI;       // 4194304
    ushort_t* inWbf  = ybf   + (size_t)M_TOT * DI;       // 4194304
    ushort_t* xpWbf  = inWbf + (size_t)2 * DI * DM;      // 196608
    ushort_t* outWbf = xpWbf + (size_t)XPD * DI;         // 2097152

    // Scan scratch Sb+Pb (2 x NC x NCH floats = 8.39 MB) overlays inWbf
    // (8.39 MB): inWbf is consumed by GEMM1 before the scan and re-converted
    // at the top of each direction. Exact-fit aliasing, no extra ws needed.
    float* Sb = (float*)inWbf;
    float* Pb = Sb + (size_t)NC * NCH;

    float* out = (float*)d_out;
    dim3 blk(256);

    f32_to_bf16<<<(M_TOT * DM) / 1024, blk, 0, stream>>>(x, xbf);

    for (int dir = 0; dir < 2; dir++) {
        int pb = 1 + dir * 9;
        const float* inW   = (const float*)d_in[pb + 0];
        const float* convW = (const float*)d_in[pb + 1];
        const float* convB = (const float*)d_in[pb + 2];
        const float* xpW   = (const float*)d_in[pb + 3];
        const float* dtW   = (const float*)d_in[pb + 4];
        const float* dtB   = (const float*)d_in[pb + 5];
        const float* Alog  = (const float*)d_in[pb + 6];
        const float* Dp    = (const float*)d_in[pb + 7];
        const float* outW  = (const float*)d_in[pb + 8];

        f32_to_bf16<<<(2 * DI * DM) / 1024, blk, 0, stream>>>(inW, inWbf);
        f32_to_bf16<<<(XPD * DI) / 1024, blk, 0, stream>>>(xpW, xpWbf);
        f32_to_bf16<<<(DM * DI) / 1024, blk, 0, stream>>>(outW, outWbf);

        // xz = X(dir) * inW^T   [2048 x 4096], K=1024
        gemm_mfma<128, 128><<<dim3((2 * DI) / 128, M_TOT / 128), blk, 0, stream>>>(
            xbf, inWbf, xz, M_TOT, 2 * DI, DM, dir, 0, 1.f, 0);

        conv_silu<<<(M_TOT * DI) / 256, blk, 0, stream>>>(xz, convW, convB, u, ubf);

        // xdbl = u * xpW^T   [2048 x 96], K=2048
        gemm_mfma<64, 64><<<dim3((XPD + 63) / 64, M_TOT / 64), blk, 0, stream>>>(
            ubf, xpWbf, xdbl, M_TOT, XPD, DI, 0, 0, 1.f, 0);

        delta_kernel<<<dim3(DI / 256, M_TOT), blk, 0, stream>>>(xdbl, dtW, dtB, delta);

        // chunked exact scan: pass1 -> combine -> pass2
        scan_pass1<<<(1024 * NC) / 4, blk, 0, stream>>>(u, xdbl, delta, Alog, Sb, Pb);
        scan_combine<<<NCH / 256, blk, 0, stream>>>(Sb, Pb);
        scan_pass2<<<(1024 * NC) / 4, blk, 0, stream>>>(xz, u, xdbl, delta, Alog, Dp,
                                                        Sb, ybf);

        // out (+)= 0.5 * y * outW^T
        gemm_mfma<64, 64><<<dim3(DM / 64, M_TOT / 64), blk, 0, stream>>>(
            ybf, outWbf, out, M_TOT, DM, DI, 0, dir, 0.5f, dir);
    }
}

// Round 4
// 719.334 us; speedup vs baseline: 4.5392x; 1.3035x over previous
//
#include <hip/hip_runtime.h>
#include <math.h>

#define B_SZ 2
#define SEQ  1024
#define DM   1024
#define DI   2048
#define NST  16
#define RNK  64
#define XPD  96            // RNK + 2*NST
#define M_TOT (B_SZ*SEQ)   // 2048
#define NC   16            // scan chunks
#define LC   (SEQ/NC)      // 64 steps per chunk
#define NCH  65536         // total chains = B_SZ*DI*NST

typedef unsigned short ushort_t;
typedef __attribute__((ext_vector_type(8))) short short8;   // 8 bf16 = 4 VGPRs
typedef __attribute__((ext_vector_type(4))) float f32x4;

__device__ __forceinline__ ushort_t f2bf(float f) {
    unsigned u = __float_as_uint(f);
    u += 0x7fff + ((u >> 16) & 1);           // round-to-nearest-even
    return (ushort_t)(u >> 16);
}

// ---------------------------------------------------------------------------
// fp32 -> bf16 bulk convert (n must be multiple of 1024; processes float4)
// ---------------------------------------------------------------------------
__global__ __launch_bounds__(256)
void f32_to_bf16(const float* __restrict__ in, ushort_t* __restrict__ out)
{
    int i = blockIdx.x * 256 + threadIdx.x;
    float4 v = ((const float4*)in)[i];
    ushort4 o;
    o.x = f2bf(v.x); o.y = f2bf(v.y); o.z = f2bf(v.z); o.w = f2bf(v.w);
    ((ushort4*)out)[i] = o;
}

// ---------------------------------------------------------------------------
// bf16 MFMA NT GEMM: D[M,N] = scale * (A[M,K] * W[N,K]^T) (+= if accum)
// ---------------------------------------------------------------------------
#define BK   64
#define LDSP 72   // padded LDS row stride (bf16 elems)

template<int BM, int BN>
__global__ __launch_bounds__(256)
void gemm_mfma(const ushort_t* __restrict__ A, const ushort_t* __restrict__ W,
               float* __restrict__ D, int M, int N, int K,
               int flipA, int flipOut, float scale, int accum)
{
    __shared__ __align__(16) ushort_t As[BM * LDSP];
    __shared__ __align__(16) ushort_t Ws[BN * LDSP];
    const int t    = threadIdx.x;
    const int lane = t & 63;
    const int wave = t >> 6;
    const int wr   = (wave >> 1) * (BM / 2);
    const int wc   = (wave & 1) * (BN / 2);
    constexpr int MT  = BM / 32;
    constexpr int NTW = BN / 32;

    f32x4 acc[MT][NTW] = {};

    const int m0 = blockIdx.y * BM;
    const int n0 = blockIdx.x * BN;
    const int srow = t >> 3;
    const int scol = (t & 7) << 3;

    for (int k0 = 0; k0 < K; k0 += BK) {
#pragma unroll
        for (int it = 0; it < BM / 32; it++) {
            int r = it * 32 + srow;
            int m = m0 + r;
            int arow = m;
            if (flipA) { int b = m >> 10, l = m & 1023; arow = (b << 10) + (1023 - l); }
            short8 v = *(const short8*)(A + (size_t)arow * K + k0 + scol);
            *(short8*)(&As[r * LDSP + scol]) = v;
        }
#pragma unroll
        for (int it = 0; it < BN / 32; it++) {
            int r = it * 32 + srow;
            int wn = n0 + r;
            short8 v = {};
            if (wn < N) v = *(const short8*)(W + (size_t)wn * K + k0 + scol);
            *(short8*)(&Ws[r * LDSP + scol]) = v;
        }
        __syncthreads();
#pragma unroll
        for (int kk = 0; kk < 2; kk++) {
            const int kc = kk * 32 + ((lane >> 4) << 3);
            short8 af[MT], bfr[NTW];
#pragma unroll
            for (int i = 0; i < MT; i++)
                af[i] = *(const short8*)(&As[(wr + i * 16 + (lane & 15)) * LDSP + kc]);
#pragma unroll
            for (int j = 0; j < NTW; j++)
                bfr[j] = *(const short8*)(&Ws[(wc + j * 16 + (lane & 15)) * LDSP + kc]);
#pragma unroll
            for (int i = 0; i < MT; i++)
#pragma unroll
                for (int j = 0; j < NTW; j++)
                    acc[i][j] = __builtin_amdgcn_mfma_f32_16x16x32_bf16(
                        af[i], bfr[j], acc[i][j], 0, 0, 0);
        }
        __syncthreads();
    }

#pragma unroll
    for (int i = 0; i < MT; i++) {
#pragma unroll
        for (int r = 0; r < 4; r++) {
            int m = m0 + wr + i * 16 + ((lane >> 4) << 2) + r;
            int b = m >> 10, l = m & 1023;
            int mo = flipOut ? ((b << 10) + (1023 - l)) : m;
#pragma unroll
            for (int j = 0; j < NTW; j++) {
                int n = n0 + wc + j * 16 + (lane & 15);
                if (n < N) {
                    float v = scale * acc[i][j][r];
                    size_t idx = (size_t)mo * N + n;
                    if (accum) D[idx] += v; else D[idx] = v;
                }
            }
        }
    }
}

// ---------------------------------------------------------------------------
// delta = softplus(dt[M,64] * dtW[DI,64]^T + dtB) as a single-K-tile MFMA
// GEMM. dt = xdbl[:, 0:64] (fp32, row stride XPD), dtW fp32; both converted
// to bf16 during LDS staging. Softplus slope at dtB~-4 (~0.02) compresses
// bf16 rounding error ~50x -> numerically safe.
// BM=BN=BK=64, grid (DI/64, M/64) = 32x32.
// ---------------------------------------------------------------------------
__global__ __launch_bounds__(256)
void delta_gemm(const float* __restrict__ xdbl, const float* __restrict__ dtW,
                const float* __restrict__ dtB, float* __restrict__ delta)
{
    __shared__ __align__(16) ushort_t As[64 * LDSP];
    __shared__ __align__(16) ushort_t Ws[64 * LDSP];
    const int t    = threadIdx.x;
    const int lane = t & 63;
    const int wave = t >> 6;
    const int wr   = (wave >> 1) * 32;
    const int wc   = (wave & 1) * 32;

    const int m0 = blockIdx.y * 64;
    const int n0 = blockIdx.x * 64;
    const int srow = t >> 2;            // 0..63
    const int scol = (t & 3) << 4;      // 0,16,32,48

    {
        const float* ap = xdbl + (size_t)(m0 + srow) * XPD + scol;
        const float* wp = dtW  + (size_t)(n0 + srow) * RNK + scol;
        float4 a[4], w[4];
#pragma unroll
        for (int q = 0; q < 4; q++) { a[q] = ((const float4*)ap)[q]; w[q] = ((const float4*)wp)[q]; }
        ushort_t* as  = &As[srow * LDSP + scol];
        ushort_t* wsp = &Ws[srow * LDSP + scol];
#pragma unroll
        for (int q = 0; q < 16; q++) {
            as[q]  = f2bf(((const float*)a)[q]);
            wsp[q] = f2bf(((const float*)w)[q]);
        }
    }
    __syncthreads();

    f32x4 acc[2][2] = {};
#pragma unroll
    for (int kk = 0; kk < 2; kk++) {
        const int kc = kk * 32 + ((lane >> 4) << 3);
        short8 af[2], bfr[2];
#pragma unroll
        for (int i = 0; i < 2; i++)
            af[i] = *(const short8*)(&As[(wr + i * 16 + (lane & 15)) * LDSP + kc]);
#pragma unroll
        for (int j = 0; j < 2; j++)
            bfr[j] = *(const short8*)(&Ws[(wc + j * 16 + (lane & 15)) * LDSP + kc]);
#pragma unroll
        for (int i = 0; i < 2; i++)
#pragma unroll
            for (int j = 0; j < 2; j++)
                acc[i][j] = __builtin_amdgcn_mfma_f32_16x16x32_bf16(
                    af[i], bfr[j], acc[i][j], 0, 0, 0);
    }

#pragma unroll
    for (int j = 0; j < 2; j++) {
        int n = n0 + wc + j * 16 + (lane & 15);
        float bn = dtB[n];
#pragma unroll
        for (int i = 0; i < 2; i++) {
#pragma unroll
            for (int r = 0; r < 4; r++) {
                int m = m0 + wr + i * 16 + ((lane >> 4) << 2) + r;
                float v = acc[i][j][r] + bn;
                float sp = (v > 20.f) ? v : log1pf(__expf(v));
                delta[(size_t)m * DI + n] = sp;
            }
        }
    }
}

// ---------------------------------------------------------------------------
// Depthwise causal conv(4) + bias + SiLU -> u (fp32) and ubf (bf16).
// Vectorized x4: one thread = 4 channels of one (b,l).
// ---------------------------------------------------------------------------
__global__ __launch_bounds__(256)
void conv_silu(const float* __restrict__ xz, const float* __restrict__ convW,
               const float* __restrict__ convB, float* __restrict__ u,
               ushort_t* __restrict__ ubf)
{
    int idx = blockIdx.x * 256 + threadIdx.x;   // over M_TOT*DI/4
    int di  = (idx & (DI / 4 - 1)) << 2;
    int m   = idx >> 9;
    int b   = m >> 10, l = m & (SEQ - 1);
    float4 wv[4];
#pragma unroll
    for (int c = 0; c < 4; c++) wv[c] = *(const float4*)(convW + (di + c) * 4);
    float4 acc = *(const float4*)(convB + di);
#pragma unroll
    for (int j = 0; j < 4; j++) {
        int ll = l - 3 + j;
        if (ll >= 0) {
            float4 xv = *(const float4*)(xz + (size_t)(b * SEQ + ll) * (2 * DI) + di);
            acc.x += ((const float*)&wv[0])[j] * xv.x;
            acc.y += ((const float*)&wv[1])[j] * xv.y;
            acc.z += ((const float*)&wv[2])[j] * xv.z;
            acc.w += ((const float*)&wv[3])[j] * xv.w;
        }
    }
    float4 s;
    s.x = acc.x / (1.f + __expf(-acc.x));
    s.y = acc.y / (1.f + __expf(-acc.y));
    s.z = acc.z / (1.f + __expf(-acc.z));
    s.w = acc.w / (1.f + __expf(-acc.w));
    *(float4*)(u + (size_t)m * DI + di) = s;
    ushort4 o;
    o.x = f2bf(s.x); o.y = f2bf(s.y); o.z = f2bf(s.z); o.w = f2bf(s.w);
    *(ushort4*)(ubf + (size_t)m * DI + di) = o;
}

// ---------------------------------------------------------------------------
// Chunked selective scan (exact: linear recurrence split into NC chunks).
// ---------------------------------------------------------------------------
#define U 8

#define P1_LOADS(P, L0)                                    \
    _Pragma("unroll")                                      \
    for (int j = 0; j < U; j++) {                          \
        int l = (L0) + j;                                  \
        P##_d[j] = dlt[l * DI];                            \
        P##_u[j] = up[l * DI];                             \
        P##_B[j] = xd[l * XPD];                            \
    }

#define P1_STEPS(P)                                        \
    _Pragma("unroll")                                      \
    for (int j = 0; j < U; j++) {                          \
        float dl = P##_d[j];                               \
        float dA = __expf(dl * a_coef);                    \
        h = h * dA + (dl * P##_u[j]) * P##_B[j];           \
        prodP *= dA;                                       \
    }

__global__ __launch_bounds__(256)
void scan_pass1(const float* __restrict__ u, const float* __restrict__ xdbl,
                const float* __restrict__ delta, const float* __restrict__ Alog,
                float* __restrict__ Sb, float* __restrict__ Pb)
{
    int tid = threadIdx.x;
    int wg  = blockIdx.x * 4 + (tid >> 6);
    int w   = wg & 1023;
    int c   = wg >> 10;
    int lane = tid & 63;
    int g = lane >> 4, n = lane & 15;
    int b = w >> 9;
    int d = ((w & 511) << 2) + g;
    int base = c * LC;

    float a_coef = -__expf(Alog[d * NST + n]);
    float h = 0.f, prodP = 1.f;

    const float* dlt = delta + (size_t)b * SEQ * DI + d + (size_t)base * DI;
    const float* up  = u     + (size_t)b * SEQ * DI + d + (size_t)base * DI;
    const float* xd  = xdbl  + (size_t)b * SEQ * XPD + RNK + n + (size_t)base * XPD;

    float pa_d[U], pa_u[U], pa_B[U];
    float pb_d[U], pb_u[U], pb_B[U];

    P1_LOADS(pa, 0);
    for (int l0 = 0; l0 < LC; l0 += 2 * U) {
        P1_LOADS(pb, l0 + U);
        P1_STEPS(pa);
        if (l0 + 2 * U < LC) { P1_LOADS(pa, l0 + 2 * U); }
        P1_STEPS(pb);
    }
    int i = c * NCH + w * 64 + lane;
    Sb[i] = h;
    Pb[i] = prodP;
}

__global__ __launch_bounds__(256)
void scan_combine(float* __restrict__ Sb, const float* __restrict__ Pb)
{
    int i = blockIdx.x * 256 + threadIdx.x;   // 0..NCH-1
    float h = 0.f;
#pragma unroll
    for (int c = 0; c < NC; c++) {
        float s = Sb[c * NCH + i];
        float p = Pb[c * NCH + i];
        Sb[c * NCH + i] = h;
        h = s + p * h;
    }
}

#define SCAN_LOADS(P, L0)                                  \
    _Pragma("unroll")                                      \
    for (int j = 0; j < U; j++) {                          \
        int l = (L0) + j;                                  \
        P##_d[j] = dlt[l * DI];                            \
        P##_u[j] = up[l * DI];                             \
        P##_B[j] = xd[l * XPD];                            \
        P##_C[j] = xd[l * XPD + NST];                      \
        P##_z[j] = zz[l * (2 * DI)];                       \
    }

#define SCAN_STEPS(P, L0)                                  \
    _Pragma("unroll")                                      \
    for (int j = 0; j < U; j++) {                          \
        float dl = P##_d[j];                               \
        float dA = __expf(dl * a_coef);                    \
        h = h * dA + (dl * P##_u[j]) * P##_B[j];           \
        float p = h * P##_C[j];                            \
        p += __shfl_xor(p, 1);                             \
        p += __shfl_xor(p, 2);                             \
        p += __shfl_xor(p, 4);                             \
        p += __shfl_xor(p, 8);                             \
        if (n == 0) {                                      \
            float yv = p + P##_u[j] * dp;                  \
            float z = P##_z[j];                            \
            yv *= z / (1.f + __expf(-z));                  \
            yp[((L0) + j) * DI] = f2bf(yv);                \
        }                                                  \
    }

__global__ __launch_bounds__(256)
void scan_pass2(const float* __restrict__ xz, const float* __restrict__ u,
                const float* __restrict__ xdbl, const float* __restrict__ delta,
                const float* __restrict__ Alog, const float* __restrict__ Dp,
                const float* __restrict__ Hinit, ushort_t* __restrict__ ybf)
{
    int tid  = threadIdx.x;
    int wg   = blockIdx.x * 4 + (tid >> 6);
    int w    = wg & 1023;
    int c    = wg >> 10;
    int lane = tid & 63;
    int g = lane >> 4, n = lane & 15;
    int b = w >> 9;
    int d = ((w & 511) << 2) + g;
    int base = c * LC;

    float a_coef = -__expf(Alog[d * NST + n]);
    float dp = Dp[d];
    float h  = Hinit[c * NCH + w * 64 + lane];

    const float* dlt = delta + (size_t)b * SEQ * DI + d + (size_t)base * DI;
    const float* up  = u     + (size_t)b * SEQ * DI + d + (size_t)base * DI;
    const float* xd  = xdbl  + (size_t)b * SEQ * XPD + RNK + n + (size_t)base * XPD;
    const float* zz  = xz    + (size_t)b * SEQ * (2 * DI) + DI + d + (size_t)base * 2 * DI;
    ushort_t*    yp  = ybf   + (size_t)b * SEQ * DI + d + (size_t)base * DI;

    float pa_d[U], pa_u[U], pa_B[U], pa_C[U], pa_z[U];
    float pb_d[U], pb_u[U], pb_B[U], pb_C[U], pb_z[U];

    SCAN_LOADS(pa, 0);
    for (int l0 = 0; l0 < LC; l0 += 2 * U) {
        SCAN_LOADS(pb, l0 + U);
        SCAN_STEPS(pa, l0);
        if (l0 + 2 * U < LC) { SCAN_LOADS(pa, l0 + 2 * U); }
        SCAN_STEPS(pb, l0 + U);
    }
}

// ---------------------------------------------------------------------------
extern "C" void kernel_launch(void* const* d_in, const int* in_sizes, int n_in,
                              void* d_out, int out_size, void* d_ws, size_t ws_size,
                              hipStream_t stream)
{
    const float* x = (const float*)d_in[0];
    float* wsf = (float*)d_ws;

    // fp32 region (elements)
    float* xz    = wsf;                           // 8388608
    float* u     = xz   + (size_t)M_TOT * 2 * DI; // 4194304
    float* xdbl  = u    + (size_t)M_TOT * DI;     // 196608
    float* delta = xdbl + (size_t)M_TOT * XPD;    // 4194304
    // bf16 region
    ushort_t* bfr    = (ushort_t*)(delta + (size_t)M_TOT * DI);
    ushort_t* xbf    = bfr;                              // 2097152
    ushort_t* ubf    = xbf   + (size_t)M_TOT * DM;       // 4194304
    ushort_t* ybf    = ubf   + (size_t)M_TOT * DI;       // 4194304
    ushort_t* inWbf  = ybf   + (size_t)M_TOT * DI;       // 4194304
    ushort_t* xpWbf  = inWbf + (size_t)2 * DI * DM;      // 196608
    ushort_t* outWbf = xpWbf + (size_t)XPD * DI;         // 2097152

    // Scan scratch Sb+Pb overlays inWbf (consumed by GEMM1 before the scan,
    // reconverted each direction). Exact-fit aliasing.
    float* Sb = (float*)inWbf;
    float* Pb = Sb + (size_t)NC * NCH;

    float* out = (float*)d_out;
    dim3 blk(256);

    f32_to_bf16<<<(M_TOT * DM) / 1024, blk, 0, stream>>>(x, xbf);

    for (int dir = 0; dir < 2; dir++) {
        int pb = 1 + dir * 9;
        const float* inW   = (const float*)d_in[pb + 0];
        const float* convW = (const float*)d_in[pb + 1];
        const float* convB = (const float*)d_in[pb + 2];
        const float* xpW   = (const float*)d_in[pb + 3];
        const float* dtW   = (const float*)d_in[pb + 4];
        const float* dtB   = (const float*)d_in[pb + 5];
        const float* Alog  = (const float*)d_in[pb + 6];
        const float* Dp    = (const float*)d_in[pb + 7];
        const float* outW  = (const float*)d_in[pb + 8];

        f32_to_bf16<<<(2 * DI * DM) / 1024, blk, 0, stream>>>(inW, inWbf);
        f32_to_bf16<<<(XPD * DI) / 1024, blk, 0, stream>>>(xpW, xpWbf);
        f32_to_bf16<<<(DM * DI) / 1024, blk, 0, stream>>>(outW, outWbf);

        // xz = X(dir) * inW^T   [2048 x 4096], K=1024
        gemm_mfma<128, 128><<<dim3((2 * DI) / 128, M_TOT / 128), blk, 0, stream>>>(
            xbf, inWbf, xz, M_TOT, 2 * DI, DM, dir, 0, 1.f, 0);

        conv_silu<<<(M_TOT * DI / 4) / 256, blk, 0, stream>>>(xz, convW, convB, u, ubf);

        // xdbl = u * xpW^T   [2048 x 96], K=2048
        gemm_mfma<64, 64><<<dim3((XPD + 63) / 64, M_TOT / 64), blk, 0, stream>>>(
            ubf, xpWbf, xdbl, M_TOT, XPD, DI, 0, 0, 1.f, 0);

        // delta = softplus(dt * dtW^T + dtB) as MFMA GEMM
        delta_gemm<<<dim3(DI / 64, M_TOT / 64), blk, 0, stream>>>(xdbl, dtW, dtB, delta);

        // chunked exact scan: pass1 -> combine -> pass2
        scan_pass1<<<(1024 * NC) / 4, blk, 0, stream>>>(u, xdbl, delta, Alog, Sb, Pb);
        scan_combine<<<NCH / 256, blk, 0, stream>>>(Sb, Pb);
        scan_pass2<<<(1024 * NC) / 4, blk, 0, stream>>>(xz, u, xdbl, delta, Alog, Dp,
                                                        Sb, ybf);

        // out (+)= 0.5 * y * outW^T
        gemm_mfma<64, 64><<<dim3(DM / 64, M_TOT / 64), blk, 0, stream>>>(
            ybf, outWbf, out, M_TOT, DM, DI, 0, dir, 0.5f, dir);
    }
}